// Round 5
// baseline (78.813 us; speedup 1.0000x reference)
//
#include <hip/hip_runtime.h>

// DRN layer, deg-4 Taylor/moment factorization, m0-normalized LDS coefficient plane.
//
//  T = exp(-w*d2), |w*d2| <= 0.097 -> deg-4 Taylor (rel err 7e-8).
//  Pw/m0 = 1 + (-w)(n1 + (-w)(n2 + (-w)(n3 + (-w) n4))),  n_i = (m_i/i!)/m0
//  m_n(k,l) = sum_p C(2n,p)(-s_l)^(2n-p) mom_p[i,k],  mom_p = sum_m s_m^p P[i,k,m]
//  sum_k log2(m0) is (j,l)-independent -> cancels in softmax. poly in [0.907,1.102]
//  so the product over all 64 k stays within 2^+-14: ONE log2 per j total.
//  softmax in base 2 (fold log2e into exponent_B).
//
// grid = 256 (one block per batch row i), block = 512 = 8 waves; lane = l.
// Wave wv owns j in [wv*8, wv*8+8). Weights preloaded per-lane (lane = k) and
// broadcast per-k via v_readlane (VALU pipe) -> k-loop touches LDS exactly once
// per (k,lane): a contiguous conflict-free ds_read_b128 of the n-plane.

#define NUP 64
#define NLOW 64
#define QUP 64
#define QLOW 64

__global__ __launch_bounds__(512, 2)
void drn_kernel(const float* __restrict__ P,
                const float* __restrict__ weight,
                const float* __restrict__ bias_abs,
                const float* __restrict__ bias_q,
                const float* __restrict__ lambda_abs,
                const float* __restrict__ lambda_q,
                float* __restrict__ out)
{
    __shared__ float  lds_mom[NLOW * 12];        // mom_0..mom_8 per k
    __shared__ float4 lds_n[NLOW * QUP];         // (n1,n2,n3,n4) per (k,l)  64 KB

    const int i    = blockIdx.x;
    const int tid  = threadIdx.x;
    const int lane = tid & 63;
    const int wv   = __builtin_amdgcn_readfirstlane(tid >> 6);   // 0..7, uniform

    // ---------------- preload weight rows for this wave's 8 j (lane = k) ----------------
    float wreg[8];
#pragma unroll
    for (int jj = 0; jj < 8; ++jj)
        wreg[jj] = weight[(size_t)(wv * 8 + jj) * NLOW + lane];

    // ---------------- phase 1: raw moments mom_0..8 ----------------
    // lane = (kk, mc): k = wv*8+kk ; m in [mc*8, mc*8+8)
    {
        const int kk = lane >> 3;
        const int mc = lane & 7;
        const int k  = wv * 8 + kk;
        const float* Pr = P + ((size_t)i * NLOW + k) * QLOW + mc * 8;
        const float4 pa = *reinterpret_cast<const float4*>(Pr);
        const float4 pb = *reinterpret_cast<const float4*>(Pr + 4);

        float t0 = 0.f, t1 = 0.f, t2 = 0.f, t3 = 0.f, t4 = 0.f,
              t5 = 0.f, t6 = 0.f, t7 = 0.f, t8 = 0.f;
        const float s0 = (float)(mc * 8) * 0.015625f;
#define ACCM(PV, S) { float f = (PV); const float s_ = (S); \
        t0 += f; f *= s_; t1 += f; f *= s_; t2 += f; f *= s_; t3 += f; f *= s_; \
        t4 += f; f *= s_; t5 += f; f *= s_; t6 += f; f *= s_; t7 += f; f *= s_; t8 += f; }
        ACCM(pa.x, s0);
        ACCM(pa.y, s0 + 0.015625f);
        ACCM(pa.z, s0 + 0.03125f);
        ACCM(pa.w, s0 + 0.046875f);
        ACCM(pb.x, s0 + 0.0625f);
        ACCM(pb.y, s0 + 0.078125f);
        ACCM(pb.z, s0 + 0.09375f);
        ACCM(pb.w, s0 + 0.109375f);
#undef ACCM
#define RED9(OFF) { t0 += __shfl_xor(t0, OFF, 64); t1 += __shfl_xor(t1, OFF, 64); \
        t2 += __shfl_xor(t2, OFF, 64); t3 += __shfl_xor(t3, OFF, 64); \
        t4 += __shfl_xor(t4, OFF, 64); t5 += __shfl_xor(t5, OFF, 64); \
        t6 += __shfl_xor(t6, OFF, 64); t7 += __shfl_xor(t7, OFF, 64); \
        t8 += __shfl_xor(t8, OFF, 64); }
        RED9(1) RED9(2) RED9(4)
#undef RED9
        if (mc == 0) {
            float* mp = &lds_mom[k * 12];
            *reinterpret_cast<float4*>(mp)     = make_float4(t0, t1, t2, t3);
            *reinterpret_cast<float4*>(mp + 4) = make_float4(t4, t5, t6, t7);
            mp[8] = t8;
        }
    }
    __syncthreads();

    // ---------------- phase 2: combine -> normalized n_i(k,l) plane ----------------
    const float s1l = (float)lane * 0.015625f;
    {
        const float z  = -s1l;
        const float z2 = z * z, z3 = z2 * z, z4 = z2 * z2;
        const float z5 = z4 * z, z6 = z4 * z2, z7 = z6 * z, z8 = z4 * z4;
        const float c10 = z2,                c11 = 2.f * z;
        const float c20 = 0.5f * z4,         c21 = 2.f * z3,          c22 = 3.f * z2,
                    c23 = 2.f * z;
        const float c30 = z6 * (1.f / 6.f),  c31 = z5,                c32 = 2.5f * z4,
                    c33 = (10.f / 3.f) * z3, c34 = 2.5f * z2,         c35 = z;
        const float c40 = z8 * (1.f / 24.f), c41 = z7 * (1.f / 3.f),  c42 = (7.f / 6.f) * z6,
                    c43 = (7.f / 3.f) * z5,  c44 = (35.f / 12.f) * z4, c45 = (7.f / 3.f) * z3,
                    c46 = (7.f / 6.f) * z2,  c47 = z * (1.f / 3.f);

#pragma unroll
        for (int kk = 0; kk < 8; ++kk) {
            const int k = wv * 8 + kk;
            const float4 q0 = *reinterpret_cast<const float4*>(&lds_mom[k * 12]);
            const float4 q1 = *reinterpret_cast<const float4*>(&lds_mom[k * 12 + 4]);
            const float  q8 = lds_mom[k * 12 + 8];

            const float inv = 1.0f / q0.x;     // 1/m0
            const float m1 = fmaf(c10, q0.x, fmaf(c11, q0.y, q0.z));
            const float m2 = fmaf(c20, q0.x, fmaf(c21, q0.y, fmaf(c22, q0.z,
                             fmaf(c23, q0.w, 0.5f * q1.x))));
            const float m3 = fmaf(c30, q0.x, fmaf(c31, q0.y, fmaf(c32, q0.z,
                             fmaf(c33, q0.w, fmaf(c34, q1.x, fmaf(c35, q1.y,
                             (1.f / 6.f) * q1.z))))));
            const float m4 = fmaf(c40, q0.x, fmaf(c41, q0.y, fmaf(c42, q0.z,
                             fmaf(c43, q0.w, fmaf(c44, q1.x, fmaf(c45, q1.y,
                             fmaf(c46, q1.z, fmaf(c47, q1.w, (1.f / 24.f) * q8))))))));

            lds_n[k * QUP + lane] = make_float4(m1 * inv, m2 * inv, m3 * inv, m4 * inv);
        }
    }
    __syncthreads();

    // ---------------- main loop: 64 k, this wave's 8 j's ----------------
    float pr[8];
#pragma unroll
    for (int jj = 0; jj < 8; ++jj) pr[jj] = 1.0f;

    for (int k8 = 0; k8 < 8; ++k8) {
#pragma unroll
        for (int kk = 0; kk < 8; ++kk) {
            const int k = k8 * 8 + kk;
            const float4 n = lds_n[k * QUP + lane];
#pragma unroll
            for (int jj = 0; jj < 8; ++jj) {
                const float w_ = __int_as_float(
                    __builtin_amdgcn_readlane(__float_as_int(wreg[jj]), k));
                float t = fmaf(-w_, n.w, n.z);
                t = fmaf(-w_, t, n.y);
                t = fmaf(-w_, t, n.x);
                pr[jj] *= fmaf(-w_, t, 1.0f);   // poly in [0.907,1.102]: clip unreachable
            }
        }
    }

    // ---------------- epilogue: exponent_B + base-2 softmax over lanes ----------------
    const float LOG2E = 1.4426950408889634f;
#pragma unroll
    for (int jj = 0; jj < 8; ++jj) {
        const int j = wv * 8 + jj;
        const float dq = s1l - lambda_q[j];
        float y = __log2f(pr[jj]);
        y = fmaf(-bias_q[j] * LOG2E, dq * dq, y);
        y = fmaf(-bias_abs[j] * LOG2E, fabsf(s1l - lambda_abs[j]), y);
        float mx = y;
#pragma unroll
        for (int off = 32; off >= 1; off >>= 1)
            mx = fmaxf(mx, __shfl_xor(mx, off, 64));
        const float e = exp2f(y - mx);
        float s = e;
#pragma unroll
        for (int off = 32; off >= 1; off >>= 1)
            s += __shfl_xor(s, off, 64);
        out[((size_t)i * NUP + j) * QUP + lane] = e / s;
    }
}

extern "C" void kernel_launch(void* const* d_in, const int* in_sizes, int n_in,
                              void* d_out, int out_size, void* d_ws, size_t ws_size,
                              hipStream_t stream) {
    const float* P          = (const float*)d_in[0];
    const float* weight     = (const float*)d_in[1];
    const float* bias_abs   = (const float*)d_in[2];
    const float* bias_q     = (const float*)d_in[3];
    const float* lambda_abs = (const float*)d_in[4];
    const float* lambda_q   = (const float*)d_in[5];
    (void)in_sizes; (void)n_in; (void)out_size; (void)d_ws; (void)ws_size;

    drn_kernel<<<dim3(256), dim3(512), 0, stream>>>(
        P, weight, bias_abs, bias_q, lambda_abs, lambda_q, (float*)d_out);
}

// Round 6
// 77.307 us; speedup vs baseline: 1.0195x; 1.0195x over previous
//
#include <hip/hip_runtime.h>

// DRN layer, deg-4 Taylor/moment factorization, m0-normalized LDS coefficient plane.
//
//  T = exp(-w*d2), |w*d2| <= 0.097 -> deg-4 Taylor (rel err 7e-8).
//  Pw/m0 = 1 + (-w)(n1 + (-w)(n2 + (-w)(n3 + (-w) n4))),  n_i = (m_i/i!)/m0
//  m_n(k,l) = sum_p C(2n,p)(-s_l)^(2n-p) mom_p[i,k],  mom_p = sum_m s_m^p P[i,k,m]
//  sum_k log2(m0) is (j,l)-independent -> cancels in softmax. poly in [0.907,1.102]
//  so |log2 prod| <= 9 and |exponent_B*log2e| <= 0.3: exp2 is fp32-safe WITHOUT
//  the max-shift -> softmax = one exp2 + one 6-stage sum butterfly per j.
//
// grid = 256 (one block per batch row i), block = 1024 = 16 waves; lane = l.
// 16 waves/CU = 4 waves/SIMD (the R5 regression was 2 waves/SIMD).
// Wave wv owns j in [wv*4, wv*4+4). Weights preloaded per-lane (lane = k) and
// broadcast per-k via v_readlane (VALU pipe, uniform index) -> k-loop touches
// LDS exactly once per (k,lane): a contiguous conflict-free ds_read_b128.

#define NUP 64
#define NLOW 64
#define QUP 64
#define QLOW 64

__global__ __launch_bounds__(1024, 1)
void drn_kernel(const float* __restrict__ P,
                const float* __restrict__ weight,
                const float* __restrict__ bias_abs,
                const float* __restrict__ bias_q,
                const float* __restrict__ lambda_abs,
                const float* __restrict__ lambda_q,
                float* __restrict__ out)
{
    __shared__ float  lds_mom[NLOW * 12];        // mom_0..mom_8 per k
    __shared__ float4 lds_n[NLOW * QUP];         // (n1,n2,n3,n4) per (k,l)  64 KB

    const int i    = blockIdx.x;
    const int tid  = threadIdx.x;
    const int lane = tid & 63;
    const int wv   = __builtin_amdgcn_readfirstlane(tid >> 6);   // 0..15, uniform

    // ---------------- preload weight rows for this wave's 4 j (lane = k) ----------------
    float wreg[4];
#pragma unroll
    for (int jj = 0; jj < 4; ++jj)
        wreg[jj] = weight[(size_t)(wv * 4 + jj) * NLOW + lane];

    // ---------------- phase 1: raw moments mom_0..8 ----------------
    // lane = (kk, mc): k = wv*4+kk (4 k per wave, 64 k over 16 waves);
    // m in [mc*4, mc*4+4) (16 lanes per k, one float4 each).
    {
        const int kk = lane >> 4;                // 0..3
        const int mc = lane & 15;                // 0..15
        const int k  = wv * 4 + kk;
        const float4 pa = *reinterpret_cast<const float4*>(
            P + ((size_t)i * NLOW + k) * QLOW + mc * 4);

        float t0 = 0.f, t1 = 0.f, t2 = 0.f, t3 = 0.f, t4 = 0.f,
              t5 = 0.f, t6 = 0.f, t7 = 0.f, t8 = 0.f;
        const float s0 = (float)(mc * 4) * 0.015625f;
#define ACCM(PV, S) { float f = (PV); const float s_ = (S); \
        t0 += f; f *= s_; t1 += f; f *= s_; t2 += f; f *= s_; t3 += f; f *= s_; \
        t4 += f; f *= s_; t5 += f; f *= s_; t6 += f; f *= s_; t7 += f; f *= s_; t8 += f; }
        ACCM(pa.x, s0);
        ACCM(pa.y, s0 + 0.015625f);
        ACCM(pa.z, s0 + 0.03125f);
        ACCM(pa.w, s0 + 0.046875f);
#undef ACCM
        // reduce over mc (lane bits 0..3)
#define RED9(OFF) { t0 += __shfl_xor(t0, OFF, 64); t1 += __shfl_xor(t1, OFF, 64); \
        t2 += __shfl_xor(t2, OFF, 64); t3 += __shfl_xor(t3, OFF, 64); \
        t4 += __shfl_xor(t4, OFF, 64); t5 += __shfl_xor(t5, OFF, 64); \
        t6 += __shfl_xor(t6, OFF, 64); t7 += __shfl_xor(t7, OFF, 64); \
        t8 += __shfl_xor(t8, OFF, 64); }
        RED9(1) RED9(2) RED9(4) RED9(8)
#undef RED9
        if (mc == 0) {
            float* mp = &lds_mom[k * 12];
            *reinterpret_cast<float4*>(mp)     = make_float4(t0, t1, t2, t3);
            *reinterpret_cast<float4*>(mp + 4) = make_float4(t4, t5, t6, t7);
            mp[8] = t8;
        }
    }
    __syncthreads();

    // ---------------- phase 2: combine -> normalized n_i(k,l) plane ----------------
    const float s1l = (float)lane * 0.015625f;
    {
        const float z  = -s1l;
        const float z2 = z * z, z3 = z2 * z, z4 = z2 * z2;
        const float z5 = z4 * z, z6 = z4 * z2, z7 = z6 * z, z8 = z4 * z4;
        const float c10 = z2,                c11 = 2.f * z;
        const float c20 = 0.5f * z4,         c21 = 2.f * z3,          c22 = 3.f * z2,
                    c23 = 2.f * z;
        const float c30 = z6 * (1.f / 6.f),  c31 = z5,                c32 = 2.5f * z4,
                    c33 = (10.f / 3.f) * z3, c34 = 2.5f * z2,         c35 = z;
        const float c40 = z8 * (1.f / 24.f), c41 = z7 * (1.f / 3.f),  c42 = (7.f / 6.f) * z6,
                    c43 = (7.f / 3.f) * z5,  c44 = (35.f / 12.f) * z4, c45 = (7.f / 3.f) * z3,
                    c46 = (7.f / 6.f) * z2,  c47 = z * (1.f / 3.f);

#pragma unroll
        for (int kk = 0; kk < 4; ++kk) {
            const int k = wv * 4 + kk;
            const float4 q0 = *reinterpret_cast<const float4*>(&lds_mom[k * 12]);
            const float4 q1 = *reinterpret_cast<const float4*>(&lds_mom[k * 12 + 4]);
            const float  q8 = lds_mom[k * 12 + 8];

            const float inv = 1.0f / q0.x;     // 1/m0
            const float m1 = fmaf(c10, q0.x, fmaf(c11, q0.y, q0.z));
            const float m2 = fmaf(c20, q0.x, fmaf(c21, q0.y, fmaf(c22, q0.z,
                             fmaf(c23, q0.w, 0.5f * q1.x))));
            const float m3 = fmaf(c30, q0.x, fmaf(c31, q0.y, fmaf(c32, q0.z,
                             fmaf(c33, q0.w, fmaf(c34, q1.x, fmaf(c35, q1.y,
                             (1.f / 6.f) * q1.z))))));
            const float m4 = fmaf(c40, q0.x, fmaf(c41, q0.y, fmaf(c42, q0.z,
                             fmaf(c43, q0.w, fmaf(c44, q1.x, fmaf(c45, q1.y,
                             fmaf(c46, q1.z, fmaf(c47, q1.w, (1.f / 24.f) * q8))))))));

            lds_n[k * QUP + lane] = make_float4(m1 * inv, m2 * inv, m3 * inv, m4 * inv);
        }
    }
    __syncthreads();

    // ---------------- main loop: 64 k, this wave's 4 j's ----------------
    float pr0 = 1.f, pr1 = 1.f, pr2 = 1.f, pr3 = 1.f;
    for (int k8 = 0; k8 < 8; ++k8) {
#pragma unroll
        for (int kk = 0; kk < 8; ++kk) {
            const int k = k8 * 8 + kk;
            const float4 n = lds_n[k * QUP + lane];
#define STEPJ(JJ, PR) { \
            const float w_ = __int_as_float( \
                __builtin_amdgcn_readlane(__float_as_int(wreg[JJ]), k)); \
            float t = fmaf(-w_, n.w, n.z); \
            t = fmaf(-w_, t, n.y); \
            t = fmaf(-w_, t, n.x); \
            PR *= fmaf(-w_, t, 1.0f); }
            STEPJ(0, pr0)
            STEPJ(1, pr1)
            STEPJ(2, pr2)
            STEPJ(3, pr3)
#undef STEPJ
        }
    }

    // ---------------- epilogue: exponent_B + base-2 softmax (no max-shift) ----------------
    const float LOG2E = 1.4426950408889634f;
    auto finish = [&](float prv, int jj) {
        const int j = wv * 4 + jj;
        const float dq = s1l - lambda_q[j];
        float y = __log2f(prv);                     // |y| <= ~9
        y = fmaf(-bias_q[j] * LOG2E, dq * dq, y);
        y = fmaf(-bias_abs[j] * LOG2E, fabsf(s1l - lambda_abs[j]), y);
        const float e = exp2f(y);                   // fp32-safe: y in [-9.3, 9.3]
        float s = e;
#pragma unroll
        for (int off = 32; off >= 1; off >>= 1)
            s += __shfl_xor(s, off, 64);
        out[((size_t)i * NUP + j) * QUP + lane] = e / s;
    };
    finish(pr0, 0);
    finish(pr1, 1);
    finish(pr2, 2);
    finish(pr3, 3);
}

extern "C" void kernel_launch(void* const* d_in, const int* in_sizes, int n_in,
                              void* d_out, int out_size, void* d_ws, size_t ws_size,
                              hipStream_t stream) {
    const float* P          = (const float*)d_in[0];
    const float* weight     = (const float*)d_in[1];
    const float* bias_abs   = (const float*)d_in[2];
    const float* bias_q     = (const float*)d_in[3];
    const float* lambda_abs = (const float*)d_in[4];
    const float* lambda_q   = (const float*)d_in[5];
    (void)in_sizes; (void)n_in; (void)out_size; (void)d_ws; (void)ws_size;

    drn_kernel<<<dim3(256), dim3(1024), 0, stream>>>(
        P, weight, bias_abs, bias_q, lambda_abs, lambda_q, (float*)d_out);
}